// Round 3
// baseline (104.941 us; speedup 1.0000x reference)
//
#include <hip/hip_runtime.h>
#include <math.h>

// Problem constants (from reference): N=8192 nodes, IN=512, OUT=8192, HEADS=1.
#define NN 8192
#define INC 512

// ---------------------------------------------------------------------------
// deg[row[e]] += 1   (float atomics; degrees << 2^24 so exact)
__global__ void deg_kernel(const int* __restrict__ row, float* __restrict__ deg, int E) {
    int e = blockIdx.x * 256 + threadIdx.x;
    if (e < E) atomicAdd(&deg[row[e]], 1.0f);
}

// dinv[i] = deg[i]^-0.5   (in place)
__global__ void dinv_kernel(float* __restrict__ deg) {
    int i = blockIdx.x * 256 + threadIdx.x;
    deg[i] = 1.0f / sqrtf(deg[i]);
}

// adv[row[e]] += dinv[col[e]]
__global__ void adv_kernel(const int* __restrict__ row, const int* __restrict__ col,
                           const float* __restrict__ dinv, float* __restrict__ adv, int E) {
    int e = blockIdx.x * 256 + threadIdx.x;
    if (e < E) atomicAdd(&adv[row[e]], dinv[col[e]]);
}

// ---------------------------------------------------------------------------
// Fused weighted column-reduction over two [8192,512] row-major matrices:
//   blocks   0..127: t[c] = sum_j dinv[j]   * x[j,c]
//   blocks 128..255: u[c] = sum_k att[k]    * lin_w[k,c]   (a1 = attention[0:8192])
//                    scal[0] (c0) += sum_k lin_b[k]*att[k]
// 64 rows per block; thread tid owns columns tid and tid+256. Coalesced reads.
__global__ void tu_kernel(const float* __restrict__ x,
                          const float* __restrict__ dinv,
                          const float* __restrict__ lin_w,
                          const float* __restrict__ att,
                          const float* __restrict__ lin_b,
                          float* __restrict__ t_out,
                          float* __restrict__ u_out,
                          float* __restrict__ scal) {
    const int b = blockIdx.x;
    const bool is_u = (b >= 128);
    const int r0 = (is_u ? b - 128 : b) * 64;
    const float* __restrict__ src = is_u ? lin_w : x;
    const float* __restrict__ rw  = is_u ? att   : dinv;
    const int tid = threadIdx.x;

    float acc0 = 0.f, acc1 = 0.f;
    #pragma unroll 4
    for (int r = r0; r < r0 + 64; ++r) {
        float w = rw[r];
        const float* __restrict__ p = src + (size_t)r * INC;
        acc0 += w * p[tid];
        acc1 += w * p[tid + 256];
    }
    float* __restrict__ dst = is_u ? u_out : t_out;
    atomicAdd(&dst[tid], acc0);
    atomicAdd(&dst[tid + 256], acc1);

    if (is_u && tid < 64) {  // wave 0 only: c0 partial over this block's 64 rows
        float v = lin_b[r0 + tid] * att[r0 + tid];
        #pragma unroll
        for (int o = 32; o > 0; o >>= 1) v += __shfl_down(v, o);
        if (tid == 0) atomicAdd(&scal[0], v);
    }
}

// ---------------------------------------------------------------------------
// s[k] = sum_c t[c] * weight[c,k]   (weight row-major [512,8192]; coalesced over k)
// scal[1] += s[k] * attention[8192+k]   (dot(s, a2))
__global__ void s_kernel(const float* __restrict__ weight,
                         const float* __restrict__ t_in,
                         const float* __restrict__ att,
                         float* __restrict__ s_out,
                         float* __restrict__ scal) {
    __shared__ float t_lds[INC];
    __shared__ float red[256];
    const int tid = threadIdx.x;
    t_lds[tid]       = t_in[tid];
    t_lds[tid + 256] = t_in[tid + 256];
    __syncthreads();

    const int k = blockIdx.x * 256 + tid;
    float acc = 0.f;
    #pragma unroll 8
    for (int c = 0; c < INC; ++c) acc += t_lds[c] * weight[(size_t)c * NN + k];
    s_out[k] = acc;

    red[tid] = acc * att[NN + k];
    __syncthreads();
    #pragma unroll
    for (int o = 128; o > 0; o >>= 1) {
        if (tid < o) red[tid] += red[tid + o];
        __syncthreads();
    }
    if (tid == 0) atomicAdd(&scal[1], red[0]);
}

// ---------------------------------------------------------------------------
// Per row i (one 64-lane wave per row):
//   xu    = x[i,:] . u
//   a     = xu + scal[0](c0) + adv[i]*scal[1](s.a2)
//   alpha = leaky_relu(a, 0.2)
//   scal[2] += s[i] * alpha           (dot(s, alpha) — alpha never materialized)
__global__ void alpha_kernel(const float* __restrict__ x,
                             const float* __restrict__ u,
                             const float* __restrict__ adv,
                             const float* __restrict__ s,
                             float* __restrict__ scal) {
    __shared__ float u_lds[INC];
    __shared__ float wsum[4];
    const int tid = threadIdx.x;
    u_lds[tid]       = u[tid];
    u_lds[tid + 256] = u[tid + 256];
    __syncthreads();

    const int wave = tid >> 6, lane = tid & 63;
    const int i = blockIdx.x * 4 + wave;
    const float* __restrict__ xr = x + (size_t)i * INC;
    float acc = 0.f;
    #pragma unroll
    for (int m = 0; m < 8; ++m) acc += xr[lane + m * 64] * u_lds[lane + m * 64];
    #pragma unroll
    for (int o = 32; o > 0; o >>= 1) acc += __shfl_down(acc, o);

    if (lane == 0) {
        float a  = acc + scal[0] + adv[i] * scal[1];
        float lr = a > 0.f ? a : 0.2f * a;
        wsum[wave] = lr * s[i];
    }
    __syncthreads();
    if (tid == 0) atomicAdd(&scal[2], wsum[0] + wsum[1] + wsum[2] + wsum[3]);
}

// ---------------------------------------------------------------------------
// out[i] = relu(adv[i] * scal[2] + bias[i])
__global__ void out_kernel(const float* __restrict__ adv,
                           const float* __restrict__ bias,
                           const float* __restrict__ scal,
                           float* __restrict__ out) {
    int i = blockIdx.x * 256 + threadIdx.x;
    float v = adv[i] * scal[2] + bias[i];
    out[i] = v > 0.f ? v : 0.f;
}

// ---------------------------------------------------------------------------
extern "C" void kernel_launch(void* const* d_in, const int* in_sizes, int n_in,
                              void* d_out, int out_size, void* d_ws, size_t ws_size,
                              hipStream_t stream) {
    const float* x      = (const float*)d_in[0];   // [8192, 512]
    const int*   eidx   = (const int*)d_in[1];     // [2, E] int32
    const float* weight = (const float*)d_in[2];   // [512, 8192]
    const float* bias   = (const float*)d_in[3];   // [8192]
    const float* att    = (const float*)d_in[4];   // [16384]
    const float* lin_w  = (const float*)d_in[5];   // [8192, 512]
    const float* lin_b  = (const float*)d_in[6];   // [8192]

    const int E = in_sizes[1] / 2;
    const int* row = eidx;
    const int* col = eidx + E;

    // workspace layout (floats)
    float* ws   = (float*)d_ws;
    float* deg  = ws;               // [8192] -> becomes dinv in place
    float* adv  = ws + NN;          // [8192]
    float* t    = ws + 2 * NN;      // [512]
    float* u    = ws + 2 * NN + INC;        // [512]
    float* scal = ws + 2 * NN + 2 * INC;    // [8]: 0=c0, 1=dot(s,a2), 2=dot(s,alpha)
    float* s    = ws + 2 * NN + 2 * INC + 8; // [8192]

    // zero all atomic accumulators (ws is poisoned 0xAA and never re-poisoned)
    hipMemsetAsync(d_ws, 0, (size_t)(2 * NN + 2 * INC + 8) * sizeof(float), stream);

    deg_kernel  <<<(E + 255) / 256, 256, 0, stream>>>(row, deg, E);
    dinv_kernel <<<NN / 256,        256, 0, stream>>>(deg);
    adv_kernel  <<<(E + 255) / 256, 256, 0, stream>>>(row, col, deg, adv, E);
    tu_kernel   <<<256,             256, 0, stream>>>(x, deg, lin_w, att, lin_b, t, u, scal);
    s_kernel    <<<NN / 256,        256, 0, stream>>>(weight, t, att, s, scal);
    alpha_kernel<<<NN / 4,          256, 0, stream>>>(x, u, adv, s, scal);
    out_kernel  <<<NN / 256,        256, 0, stream>>>(adv, bias, scal, (float*)d_out);
}

// Round 4
// 78.823 us; speedup vs baseline: 1.3313x; 1.3313x over previous
//
#include <hip/hip_runtime.h>
#include <math.h>

// Problem constants: N=8192 nodes, IN=512, OUT=8192, HEADS=1.
#define NN 8192
#define INC 512

// ws layout (floats): deg[NN] | adv[NN] | t[INC] | u[INC] | scal[8] | s[NN]
#define WS_FLOATS (3 * NN + 2 * INC + 8)

// ---------------------------------------------------------------------------
// Zero the accumulator region of ws (replaces the 40us fillBufferAligned).
__global__ void init_kernel(float* __restrict__ ws) {
    int i = blockIdx.x * 256 + threadIdx.x;
    if (i < WS_FLOATS) ws[i] = 0.f;
}

// ---------------------------------------------------------------------------
// deg[row[e]] += 1  (int4 edge loads; float atomics exact for deg << 2^24)
__global__ void deg_kernel(const int* __restrict__ row, float* __restrict__ deg, int E) {
    int i = (blockIdx.x * 256 + threadIdx.x) * 4;
    if (i + 3 < E) {
        int4 r = *(const int4*)(row + i);
        atomicAdd(&deg[r.x], 1.f); atomicAdd(&deg[r.y], 1.f);
        atomicAdd(&deg[r.z], 1.f); atomicAdd(&deg[r.w], 1.f);
    } else {
        for (int e = i; e < E; ++e) atomicAdd(&deg[row[e]], 1.f);
    }
}

// dinv[i] = deg[i]^-0.5  (in place)
__global__ void dinv_kernel(float* __restrict__ deg) {
    int i = blockIdx.x * 256 + threadIdx.x;
    deg[i] = 1.0f / sqrtf(deg[i]);
}

// adv[row[e]] += dinv[col[e]]  (dinv is 32KB -> L1/L2-resident gather)
__global__ void adv_kernel(const int* __restrict__ row, const int* __restrict__ col,
                           const float* __restrict__ dinv, float* __restrict__ adv, int E) {
    int i = (blockIdx.x * 256 + threadIdx.x) * 4;
    if (i + 3 < E) {
        int4 r = *(const int4*)(row + i);
        int4 c = *(const int4*)(col + i);
        atomicAdd(&adv[r.x], dinv[c.x]); atomicAdd(&adv[r.y], dinv[c.y]);
        atomicAdd(&adv[r.z], dinv[c.z]); atomicAdd(&adv[r.w], dinv[c.w]);
    } else {
        for (int e = i; e < E; ++e) atomicAdd(&adv[row[e]], dinv[col[e]]);
    }
}

// ---------------------------------------------------------------------------
// Weighted column-reductions over two [8192,512] row-major matrices (float4):
//   blocks   0..127: t[c] = sum_j dinv[j] * x[j,c]
//   blocks 128..255: u[c] = sum_k att[k]  * lin_w[k,c];  scal[0] += lin_b.a1
// Each block: 64 rows. Thread layout: half = tid>>7 picks even/odd rows,
// c4 = tid&127 picks the float4 column. LDS-combine halves, 1 atomic/addr/block.
__global__ void tu_kernel(const float* __restrict__ x,
                          const float* __restrict__ dinv,
                          const float* __restrict__ lin_w,
                          const float* __restrict__ att,
                          const float* __restrict__ lin_b,
                          float* __restrict__ t_out,
                          float* __restrict__ u_out,
                          float* __restrict__ scal) {
    const int b = blockIdx.x;
    const bool is_u = (b >= 128);
    const int r0 = (is_u ? b - 128 : b) * 64;
    const float* __restrict__ src = is_u ? lin_w : x;
    const float* __restrict__ rw  = is_u ? att   : dinv;
    const int tid  = threadIdx.x;
    const int half = tid >> 7;
    const int c4   = tid & 127;

    float4 acc = {0.f, 0.f, 0.f, 0.f};
    #pragma unroll 8
    for (int r = r0 + half; r < r0 + 64; r += 2) {
        float w = rw[r];
        float4 v = ((const float4*)(src + (size_t)r * INC))[c4];
        acc.x += w * v.x; acc.y += w * v.y; acc.z += w * v.z; acc.w += w * v.w;
    }

    __shared__ float4 lds[128];
    if (half) lds[c4] = acc;
    __syncthreads();
    if (!half) {
        float4 o = lds[c4];
        float* __restrict__ dst = is_u ? u_out : t_out;
        atomicAdd(&dst[4 * c4 + 0], acc.x + o.x);
        atomicAdd(&dst[4 * c4 + 1], acc.y + o.y);
        atomicAdd(&dst[4 * c4 + 2], acc.z + o.z);
        atomicAdd(&dst[4 * c4 + 3], acc.w + o.w);
    }

    if (is_u && tid < 64) {  // c0 partial over this block's 64 rows
        float v = lin_b[r0 + tid] * att[r0 + tid];
        #pragma unroll
        for (int o = 32; o > 0; o >>= 1) v += __shfl_down(v, o);
        if (tid == 0) atomicAdd(&scal[0], v);
    }
}

// ---------------------------------------------------------------------------
// s[k] = sum_c t[c] * weight[c,k], split over 256 blocks:
//   kb = blockIdx&7  -> k-chunk of 1024 (256 threads x float4)
//   cb = blockIdx>>3 -> c-chunk of 16
// Partial s via atomics (32-way per address). Also accumulates the block's
// partial of scal[1] = sum_{c,k} t[c]*W[c,k]*a2[k]  (== dot(s, a2)).
__global__ void s_kernel(const float* __restrict__ weight,
                         const float* __restrict__ t_in,
                         const float* __restrict__ att,
                         float* __restrict__ s_out,
                         float* __restrict__ scal) {
    const int kb = blockIdx.x & 7;
    const int cb = blockIdx.x >> 3;
    const int tid = threadIdx.x;
    const int k = kb * 1024 + tid * 4;

    __shared__ float t_lds[16];
    if (tid < 16) t_lds[tid] = t_in[cb * 16 + tid];
    __syncthreads();

    const float* __restrict__ wp = weight + (size_t)(cb * 16) * NN + k;
    float4 acc = {0.f, 0.f, 0.f, 0.f};
    #pragma unroll
    for (int c = 0; c < 16; ++c) {
        float4 v = *(const float4*)(wp + (size_t)c * NN);
        float tc = t_lds[c];
        acc.x += tc * v.x; acc.y += tc * v.y; acc.z += tc * v.z; acc.w += tc * v.w;
    }
    atomicAdd(&s_out[k + 0], acc.x);
    atomicAdd(&s_out[k + 1], acc.y);
    atomicAdd(&s_out[k + 2], acc.z);
    atomicAdd(&s_out[k + 3], acc.w);

    float4 a2 = *(const float4*)(att + NN + k);
    float p = acc.x * a2.x + acc.y * a2.y + acc.z * a2.z + acc.w * a2.w;
    #pragma unroll
    for (int o = 32; o > 0; o >>= 1) p += __shfl_down(p, o);
    __shared__ float wred[4];
    if ((tid & 63) == 0) wred[tid >> 6] = p;
    __syncthreads();
    if (tid == 0) atomicAdd(&scal[1], wred[0] + wred[1] + wred[2] + wred[3]);
}

// ---------------------------------------------------------------------------
// Per row i:  alpha_i = leaky_relu(x[i].u + c0 + adv[i]*scal1, 0.2)
//             scal[2] += s[i] * alpha_i     (alpha never materialized)
// One wave handles 4 rows; float4 loads (2 per lane per row).
__global__ void alpha_kernel(const float* __restrict__ x,
                             const float* __restrict__ u,
                             const float* __restrict__ adv,
                             const float* __restrict__ s,
                             float* __restrict__ scal) {
    __shared__ float4 u_lds[128];
    __shared__ float wsum[4];
    const int tid = threadIdx.x;
    if (tid < 128) u_lds[tid] = ((const float4*)u)[tid];
    __syncthreads();

    const int wave = tid >> 6, lane = tid & 63;
    const int i0 = blockIdx.x * 16 + wave * 4;
    float acc[4] = {0.f, 0.f, 0.f, 0.f};
    #pragma unroll
    for (int r = 0; r < 4; ++r) {
        const float4* __restrict__ xr = (const float4*)(x + (size_t)(i0 + r) * INC);
        #pragma unroll
        for (int m = 0; m < 2; ++m) {
            float4 v = xr[lane + m * 64];
            float4 uu = u_lds[lane + m * 64];
            acc[r] += v.x * uu.x + v.y * uu.y + v.z * uu.z + v.w * uu.w;
        }
    }
    #pragma unroll
    for (int r = 0; r < 4; ++r)
        #pragma unroll
        for (int o = 32; o > 0; o >>= 1) acc[r] += __shfl_down(acc[r], o);

    if (lane == 0) {
        float c0 = scal[0], s1 = scal[1];
        float psum = 0.f;
        #pragma unroll
        for (int r = 0; r < 4; ++r) {
            float a  = acc[r] + c0 + adv[i0 + r] * s1;
            float lr = a > 0.f ? a : 0.2f * a;
            psum += lr * s[i0 + r];
        }
        wsum[wave] = psum;
    }
    __syncthreads();
    if (tid == 0) atomicAdd(&scal[2], wsum[0] + wsum[1] + wsum[2] + wsum[3]);
}

// ---------------------------------------------------------------------------
// out[i] = relu(adv[i] * scal[2] + bias[i])
__global__ void out_kernel(const float* __restrict__ adv,
                           const float* __restrict__ bias,
                           const float* __restrict__ scal,
                           float* __restrict__ out) {
    int i = blockIdx.x * 256 + threadIdx.x;
    float v = adv[i] * scal[2] + bias[i];
    out[i] = v > 0.f ? v : 0.f;
}

// ---------------------------------------------------------------------------
extern "C" void kernel_launch(void* const* d_in, const int* in_sizes, int n_in,
                              void* d_out, int out_size, void* d_ws, size_t ws_size,
                              hipStream_t stream) {
    const float* x      = (const float*)d_in[0];   // [8192, 512]
    const int*   eidx   = (const int*)d_in[1];     // [2, E]
    const float* weight = (const float*)d_in[2];   // [512, 8192]
    const float* bias   = (const float*)d_in[3];   // [8192]
    const float* att    = (const float*)d_in[4];   // [16384]
    const float* lin_w  = (const float*)d_in[5];   // [8192, 512]
    const float* lin_b  = (const float*)d_in[6];   // [8192]

    const int E = in_sizes[1] / 2;
    const int* row = eidx;
    const int* col = eidx + E;

    float* ws   = (float*)d_ws;
    float* deg  = ws;                         // [NN] -> dinv in place
    float* adv  = ws + NN;                    // [NN]
    float* t    = ws + 2 * NN;                // [INC]
    float* u    = ws + 2 * NN + INC;          // [INC]
    float* scal = ws + 2 * NN + 2 * INC;      // [8]: 0=c0, 1=dot(s,a2), 2=dot(s,alpha)
    float* s    = ws + 2 * NN + 2 * INC + 8;  // [NN]

    const int egrid = (E / 4 + 255) / 256;

    init_kernel <<<(WS_FLOATS + 255) / 256, 256, 0, stream>>>(ws);
    deg_kernel  <<<egrid,    256, 0, stream>>>(row, deg, E);
    dinv_kernel <<<NN / 256, 256, 0, stream>>>(deg);
    adv_kernel  <<<egrid,    256, 0, stream>>>(row, col, deg, adv, E);
    tu_kernel   <<<256,      256, 0, stream>>>(x, deg, lin_w, att, lin_b, t, u, scal);
    s_kernel    <<<256,      256, 0, stream>>>(weight, t, att, s, scal);
    alpha_kernel<<<NN / 16,  256, 0, stream>>>(x, u, adv, s, scal);
    out_kernel  <<<NN / 256, 256, 0, stream>>>(adv, bias, scal, (float*)d_out);
}